// Round 1
// baseline (275.111 us; speedup 1.0000x reference)
//
#include <hip/hip_runtime.h>
#include <hip/hip_bf16.h>

#define DEV __device__ __forceinline__

typedef __bf16 bf16;
typedef __bf16 bf16x4 __attribute__((ext_vector_type(4)));
typedef __bf16 bf16x8 __attribute__((ext_vector_type(8)));
typedef float f32x4 __attribute__((ext_vector_type(4)));

static constexpr int Bb = 4, Ll = 2048, Dd = 512, Ee = 8, Hh = 1024;
static constexpr int Mm = Bb * Ll;  // 8192 tokens

// ---------------- async global->LDS (16B per lane, wave-uniform LDS base) ---
DEV void gload_lds16(const void* g, void* l) {
  __builtin_amdgcn_global_load_lds(
      (const __attribute__((address_space(1))) unsigned int*)g,
      (__attribute__((address_space(3))) unsigned int*)l, 16, 0, 0);
}

// ---------------- elementwise f32 -> bf16 -----------------------------------
__global__ void cvt_x_kernel(const float* __restrict__ in, bf16* __restrict__ out, int n4) {
  int i = blockIdx.x * blockDim.x + threadIdx.x;
  if (i < n4) {
    float4 v = ((const float4*)in)[i];
    bf16x4 o = {(bf16)v.x, (bf16)v.y, (bf16)v.z, (bf16)v.w};
    ((bf16x4*)out)[i] = o;
  }
}

// ---------------- tiled transpose + convert ---------------------------------
// in:  f32 [R][C] per expert slab (in + e*in_es)
// out: bf16, out[(c)*out_rs + r] at (out + e*out_es)
__global__ void transpose_cvt(const float* __restrict__ in, bf16* __restrict__ out,
                              int R, int C, size_t in_es, size_t out_es, int out_rs) {
  __shared__ float tile[64][65];
  const int e = blockIdx.z;
  const float* ip = in + (size_t)e * in_es;
  bf16* op = out + (size_t)e * out_es;
  const int r0 = blockIdx.y * 64, c0 = blockIdx.x * 64;
  const int tc = threadIdx.x & 63, tr = threadIdx.x >> 6;
#pragma unroll
  for (int i = 0; i < 16; ++i) {
    const int r = tr + i * 4;
    tile[r][tc] = ip[(size_t)(r0 + r) * C + c0 + tc];
  }
  __syncthreads();
  const int wr = threadIdx.x & 63, wc0 = threadIdx.x >> 6;
#pragma unroll
  for (int i = 0; i < 16; ++i) {
    const int c = wc0 + i * 4;
    op[(size_t)(c0 + c) * out_rs + r0 + wr] = (bf16)tile[wr][c];
  }
}

// ---------------- 128x128 bf16 MFMA GEMM core (BK=64) -----------------------
// A: [128 rows][K] row-major (row stride a_rs elements)
// B: B^T layout, [128 rows = N][K] row-major (row stride b_rs elements)
// LDS tiles XOR-swizzled: seg' = seg ^ (row&7) (8 segs of 16B per 128B row).
// Staged via global_load_lds (linear LDS dest, pre-swizzled global source).
DEV void gemm_core(const bf16* __restrict__ Ag, size_t a_rs,
                   const bf16* __restrict__ Bg, size_t b_rs,
                   int ksteps, f32x4 (&acc)[4][4], bf16* As, bf16* Bs) {
  const int t = threadIdx.x;
  const int lane = t & 63;
  const int w = t >> 6;         // wave 0..3
  const int srow = t >> 3;      // staging row within a 32-row issue
  const int sseg = t & 7;       // staging 16B segment
  const int wr = w >> 1, wc = w & 1;
  const int fr = lane & 15;     // fragment row/col
  const int fg = lane >> 4;     // k-group 0..3

  for (int s = 0; s < ksteps; ++s) {
    __syncthreads();  // previous iteration's reads done before overwrite
#pragma unroll
    for (int i = 0; i < 4; ++i) {
      const int row = i * 32 + srow;
      const int q = sseg ^ (row & 7);  // pre-swizzle the global source
      gload_lds16(Ag + (size_t)row * a_rs + s * 64 + q * 8,
                  (char*)As + i * 4096 + w * 1024);
      gload_lds16(Bg + (size_t)row * b_rs + s * 64 + q * 8,
                  (char*)Bs + i * 4096 + w * 1024);
    }
    __syncthreads();  // staging (vmcnt) drained by barrier
#pragma unroll
    for (int kk = 0; kk < 2; ++kk) {
      bf16x8 af[4], bfr[4];
#pragma unroll
      for (int mi = 0; mi < 4; ++mi) {
        const int row = wr * 64 + mi * 16 + fr;
        const int q = (kk * 4 + fg) ^ (row & 7);
        af[mi] = *(const bf16x8*)((const char*)As + row * 128 + q * 16);
      }
#pragma unroll
      for (int ni = 0; ni < 4; ++ni) {
        const int row = wc * 64 + ni * 16 + fr;
        const int q = (kk * 4 + fg) ^ (row & 7);
        bfr[ni] = *(const bf16x8*)((const char*)Bs + row * 128 + q * 16);
      }
#pragma unroll
      for (int mi = 0; mi < 4; ++mi)
#pragma unroll
        for (int ni = 0; ni < 4; ++ni)
          acc[mi][ni] = __builtin_amdgcn_mfma_f32_16x16x32_bf16(
              af[mi], bfr[ni], acc[mi][ni], 0, 0, 0);
    }
  }
}

// ---------------- stage 1: g = w[m,e] * gelu(x @ W1_e + b1_e) ---------------
__global__ __launch_bounds__(256) void ffn_stage1(
    const bf16* __restrict__ xb, const bf16* __restrict__ w1t,
    const float* __restrict__ b1, const float* __restrict__ wts,
    bf16* __restrict__ G, int e0, int gks) {
  __shared__ __align__(16) bf16 As[128 * 64];
  __shared__ __align__(16) bf16 Bs[128 * 64];
  const int mt = blockIdx.x, ht = blockIdx.y, le = blockIdx.z;
  const int e = e0 + le;
  f32x4 acc[4][4] = {};
  const bf16* Ag = xb + (size_t)mt * 128 * Dd;
  const bf16* Bg = w1t + ((size_t)e * Hh + (size_t)ht * 128) * Dd;
  gemm_core(Ag, Dd, Bg, Dd, Dd / 64, acc, As, Bs);

  const int t = threadIdx.x;
  const int lane = t & 63, w = t >> 6;
  const int wr = w >> 1, wc = w & 1, fr = lane & 15, fq = lane >> 4;
#pragma unroll
  for (int mi = 0; mi < 4; ++mi) {
#pragma unroll
    for (int r = 0; r < 4; ++r) {
      const int m = mt * 128 + wr * 64 + mi * 16 + fq * 4 + r;
      const float wgt = wts[(size_t)m * Ee + e];
#pragma unroll
      for (int ni = 0; ni < 4; ++ni) {
        const int h = ht * 128 + wc * 64 + ni * 16 + fr;
        float v = acc[mi][ni][r] + b1[e * Hh + h];
        v = 0.5f * v * (1.0f + erff(v * 0.70710678118654752f));  // exact gelu
        G[(size_t)m * gks + (size_t)le * Hh + h] = (bf16)(v * wgt);
      }
    }
  }
}

// ---------------- stage 2: out (+)= G @ W2cat (+ sum_e w*b2) ----------------
__global__ __launch_bounds__(256) void ffn_stage2(
    const bf16* __restrict__ G, const bf16* __restrict__ w2t,
    const float* __restrict__ b2, const float* __restrict__ wts,
    float* __restrict__ out, int e0, int gks, int first) {
  __shared__ __align__(16) bf16 As[128 * 64];
  __shared__ __align__(16) bf16 Bs[128 * 64];
  __shared__ float b2s[Ee][128];
  __shared__ float wls[128][Ee];
  const int mt = blockIdx.x, nt = blockIdx.y;
  const int t = threadIdx.x;
  if (first) {
    for (int i = t; i < Ee * 128; i += 256) {
      const int ee = i >> 7, d = i & 127;
      b2s[ee][d] = b2[ee * Dd + nt * 128 + d];
    }
    for (int i = t; i < 128 * Ee; i += 256) {
      const int r = i >> 3, ee = i & 7;
      wls[r][ee] = wts[((size_t)mt * 128 + r) * Ee + ee];
    }
  }
  f32x4 acc[4][4] = {};
  const bf16* Ag = G + (size_t)mt * 128 * gks;
  const bf16* Bg = w2t + (size_t)nt * 128 * ((size_t)Ee * Hh) + (size_t)e0 * Hh;
  gemm_core(Ag, gks, Bg, (size_t)Ee * Hh, gks / 64, acc, As, Bs);

  const int lane = t & 63, w = t >> 6;
  const int wr = w >> 1, wc = w & 1, fr = lane & 15, fq = lane >> 4;
#pragma unroll
  for (int mi = 0; mi < 4; ++mi) {
#pragma unroll
    for (int r = 0; r < 4; ++r) {
      const int lrow = wr * 64 + mi * 16 + fq * 4 + r;
      const size_t m = (size_t)mt * 128 + lrow;
#pragma unroll
      for (int ni = 0; ni < 4; ++ni) {
        const int lcol = wc * 64 + ni * 16 + fr;
        const size_t oidx = m * Dd + nt * 128 + lcol;
        float v = acc[mi][ni][r];
        if (first) {
          float bias = 0.f;
#pragma unroll
          for (int ee = 0; ee < Ee; ++ee) bias += wls[lrow][ee] * b2s[ee][lcol];
          out[oidx] = v + bias;
        } else {
          out[oidx] += v;
        }
      }
    }
  }
}

// ---------------- launch ----------------------------------------------------
extern "C" void kernel_launch(void* const* d_in, const int* in_sizes, int n_in,
                              void* d_out, int out_size, void* d_ws, size_t ws_size,
                              hipStream_t stream) {
  const float* x   = (const float*)d_in[0];
  const float* wts = (const float*)d_in[1];
  const float* w1  = (const float*)d_in[2];
  const float* b1  = (const float*)d_in[3];
  const float* w2  = (const float*)d_in[4];
  const float* b2  = (const float*)d_in[5];
  float* out = (float*)d_out;

  char* ws = (char*)d_ws;
  size_t off = 0;
  bf16* xb  = (bf16*)(ws + off); off += (size_t)Mm * Dd * 2;        // 8 MB
  bf16* w1t = (bf16*)(ws + off); off += (size_t)Ee * Hh * Dd * 2;   // 8 MB
  bf16* w2t = (bf16*)(ws + off); off += (size_t)Dd * Ee * Hh * 2;   // 8 MB
  bf16* G   = (bf16*)(ws + off);
  size_t avail = ws_size > off ? ws_size - off : 0;
  size_t slab = (size_t)Mm * Hh * 2;  // per-expert G slab, 16 MB
  int Ec = (int)(avail / slab);
  if (Ec < 1) Ec = 1;
  if (Ec > Ee) Ec = Ee;

  cvt_x_kernel<<<(Mm * Dd / 4 + 255) / 256, 256, 0, stream>>>(x, xb, Mm * Dd / 4);
  // w1 [e][512][1024] -> W1T[e][h][d]
  transpose_cvt<<<dim3(Hh / 64, Dd / 64, Ee), 256, 0, stream>>>(
      w1, w1t, Dd, Hh, (size_t)Dd * Hh, (size_t)Hh * Dd, Dd);
  // w2 [e][1024][512] -> W2T[d][e*1024+h]
  transpose_cvt<<<dim3(Dd / 64, Hh / 64, Ee), 256, 0, stream>>>(
      w2, w2t, Hh, Dd, (size_t)Hh * Dd, (size_t)Hh, Ee * Hh);

  int first = 1;
  for (int e0 = 0; e0 < Ee;) {
    const int ec = (Ee - e0 < Ec) ? (Ee - e0) : Ec;
    const int gks = ec * Hh;
    ffn_stage1<<<dim3(Mm / 128, Hh / 128, ec), 256, 0, stream>>>(
        xb, w1t, b1, wts, G, e0, gks);
    ffn_stage2<<<dim3(Mm / 128, Dd / 128), 256, 0, stream>>>(
        G, w2t, b2, wts, out, e0, gks, first);
    e0 += ec;
    first = 0;
  }
}

// Round 2
// 252.759 us; speedup vs baseline: 1.0884x; 1.0884x over previous
//
#include <hip/hip_runtime.h>
#include <hip/hip_bf16.h>

#define DEV __device__ __forceinline__

typedef __bf16 bf16;
typedef __bf16 bf16x4 __attribute__((ext_vector_type(4)));
typedef __bf16 bf16x8 __attribute__((ext_vector_type(8)));
typedef float f32x4 __attribute__((ext_vector_type(4)));

static constexpr int Bb = 4, Ll = 2048, Dd = 512, Ee = 8, Hh = 1024;
static constexpr int Mm = Bb * Ll;  // 8192 tokens

// ---------------- async global->LDS (16B per lane, wave-uniform LDS base) ---
DEV void gload_lds16(const void* g, void* l) {
  __builtin_amdgcn_global_load_lds(
      (const __attribute__((address_space(1))) unsigned int*)g,
      (__attribute__((address_space(3))) unsigned int*)l, 16, 0, 0);
}

// fast exact-enough gelu: tanh form, g = h - h/(exp(2y)+1), y=c*(h+0.044715h^3)
DEV float gelu_fast(float h) {
  const float k = 0.7978845608028654f * 2.0f * 1.4426950408889634f;  // 2*sqrt(2/pi)*log2(e)
  float h2 = h * h;
  float y = h * (k + (0.044715f * k) * h2);   // 2*log2e*0.79788*(h+0.044715h^3)
  float t = exp2f(y);
  return h - h * __frcp_rn(t + 1.0f);
}

// ---------------- elementwise f32 -> bf16 -----------------------------------
__global__ void cvt_x_kernel(const float* __restrict__ in, bf16* __restrict__ out, int n4) {
  int i = blockIdx.x * blockDim.x + threadIdx.x;
  if (i < n4) {
    float4 v = ((const float4*)in)[i];
    bf16x4 o = {(bf16)v.x, (bf16)v.y, (bf16)v.z, (bf16)v.w};
    ((bf16x4*)out)[i] = o;
  }
}

// ---------------- tiled transpose + convert ---------------------------------
__global__ void transpose_cvt(const float* __restrict__ in, bf16* __restrict__ out,
                              int R, int C, size_t in_es, size_t out_es, int out_rs) {
  __shared__ float tile[64][65];
  const int e = blockIdx.z;
  const float* ip = in + (size_t)e * in_es;
  bf16* op = out + (size_t)e * out_es;
  const int r0 = blockIdx.y * 64, c0 = blockIdx.x * 64;
  const int tc = threadIdx.x & 63, tr = threadIdx.x >> 6;
#pragma unroll
  for (int i = 0; i < 16; ++i) {
    const int r = tr + i * 4;
    tile[r][tc] = ip[(size_t)(r0 + r) * C + c0 + tc];
  }
  __syncthreads();
  const int wr = threadIdx.x & 63, wc0 = threadIdx.x >> 6;
#pragma unroll
  for (int i = 0; i < 16; ++i) {
    const int c = wc0 + i * 4;
    op[(size_t)(c0 + c) * out_rs + r0 + wr] = (bf16)tile[wr][c];
  }
}

// ---------------- 128x128 bf16 MFMA GEMM core (BK=64) -----------------------
DEV void gemm_core(const bf16* __restrict__ Ag, size_t a_rs,
                   const bf16* __restrict__ Bg, size_t b_rs,
                   int ksteps, f32x4 (&acc)[4][4], bf16* As, bf16* Bs) {
  const int t = threadIdx.x;
  const int lane = t & 63;
  const int w = t >> 6;         // wave 0..3
  const int srow = t >> 3;      // staging row within a 32-row issue
  const int sseg = t & 7;       // staging 16B segment
  const int wr = w >> 1, wc = w & 1;
  const int fr = lane & 15;     // fragment row/col
  const int fg = lane >> 4;     // k-group 0..3

  for (int s = 0; s < ksteps; ++s) {
    __syncthreads();
#pragma unroll
    for (int i = 0; i < 4; ++i) {
      const int row = i * 32 + srow;
      const int q = sseg ^ (row & 7);  // pre-swizzle the global source
      gload_lds16(Ag + (size_t)row * a_rs + s * 64 + q * 8,
                  (char*)As + i * 4096 + w * 1024);
      gload_lds16(Bg + (size_t)row * b_rs + s * 64 + q * 8,
                  (char*)Bs + i * 4096 + w * 1024);
    }
    __syncthreads();
#pragma unroll
    for (int kk = 0; kk < 2; ++kk) {
      bf16x8 af[4], bfr[4];
#pragma unroll
      for (int mi = 0; mi < 4; ++mi) {
        const int row = wr * 64 + mi * 16 + fr;
        const int q = (kk * 4 + fg) ^ (row & 7);
        af[mi] = *(const bf16x8*)((const char*)As + row * 128 + q * 16);
      }
#pragma unroll
      for (int ni = 0; ni < 4; ++ni) {
        const int row = wc * 64 + ni * 16 + fr;
        const int q = (kk * 4 + fg) ^ (row & 7);
        bfr[ni] = *(const bf16x8*)((const char*)Bs + row * 128 + q * 16);
      }
#pragma unroll
      for (int mi = 0; mi < 4; ++mi)
#pragma unroll
        for (int ni = 0; ni < 4; ++ni)
          acc[mi][ni] = __builtin_amdgcn_mfma_f32_16x16x32_bf16(
              af[mi], bfr[ni], acc[mi][ni], 0, 0, 0);
    }
  }
}

// ---------------- stage 1: g = w[m,e] * gelu(x @ W1_e + b1_e) ---------------
__global__ __launch_bounds__(256) void ffn_stage1(
    const bf16* __restrict__ xb, const bf16* __restrict__ w1t,
    const float* __restrict__ b1, const float* __restrict__ wts,
    bf16* __restrict__ G, int e0, int gks) {
  __shared__ __align__(16) bf16 As[128 * 64];
  __shared__ __align__(16) bf16 Bs[128 * 64];
  const int mt = blockIdx.x, ht = blockIdx.y, le = blockIdx.z;
  const int e = e0 + le;
  f32x4 acc[4][4] = {};
  const bf16* Ag = xb + (size_t)mt * 128 * Dd;
  const bf16* Bg = w1t + ((size_t)e * Hh + (size_t)ht * 128) * Dd;
  gemm_core(Ag, Dd, Bg, Dd, Dd / 64, acc, As, Bs);

  const int t = threadIdx.x;
  const int lane = t & 63, w = t >> 6;
  const int wr = w >> 1, wc = w & 1, fr = lane & 15, fq = lane >> 4;
#pragma unroll
  for (int mi = 0; mi < 4; ++mi) {
#pragma unroll
    for (int r = 0; r < 4; ++r) {
      const int m = mt * 128 + wr * 64 + mi * 16 + fq * 4 + r;
      const float wgt = wts[(size_t)m * Ee + e];
#pragma unroll
      for (int ni = 0; ni < 4; ++ni) {
        const int h = ht * 128 + wc * 64 + ni * 16 + fr;
        float v = acc[mi][ni][r] + b1[e * Hh + h];
        G[(size_t)m * gks + (size_t)le * Hh + h] = (bf16)(gelu_fast(v) * wgt);
      }
    }
  }
}

// ---------------- stage 2 split-K partial: P[s] = G_chunk @ W2_chunk --------
__global__ __launch_bounds__(256) void ffn_stage2_partial(
    const bf16* __restrict__ G, const bf16* __restrict__ w2t,
    float* __restrict__ P, int gks, int kchunk) {
  __shared__ __align__(16) bf16 As[128 * 64];
  __shared__ __align__(16) bf16 Bs[128 * 64];
  const int mt = blockIdx.x, nt = blockIdx.y, s = blockIdx.z;
  f32x4 acc[4][4] = {};
  const bf16* Ag = G + (size_t)mt * 128 * gks + (size_t)s * kchunk;
  const bf16* Bg = w2t + (size_t)nt * 128 * (size_t)(Ee * Hh) + (size_t)s * kchunk;
  gemm_core(Ag, gks, Bg, (size_t)Ee * Hh, kchunk / 64, acc, As, Bs);

  float* Pp = P + (size_t)s * Mm * Dd;
  const int t = threadIdx.x;
  const int lane = t & 63, w = t >> 6;
  const int wr = w >> 1, wc = w & 1, fr = lane & 15, fq = lane >> 4;
#pragma unroll
  for (int mi = 0; mi < 4; ++mi)
#pragma unroll
    for (int r = 0; r < 4; ++r) {
      const size_t m = (size_t)mt * 128 + wr * 64 + mi * 16 + fq * 4 + r;
#pragma unroll
      for (int ni = 0; ni < 4; ++ni) {
        const int d = nt * 128 + wc * 64 + ni * 16 + fr;
        Pp[m * Dd + d] = acc[mi][ni][r];
      }
    }
}

// ---------------- reduce partials + bias ------------------------------------
__global__ __launch_bounds__(256) void reduce_bias(
    const float* __restrict__ P, const float* __restrict__ wts,
    const float* __restrict__ b2, float* __restrict__ out, int S) {
  const int n4 = Mm * Dd / 4;
  int i = blockIdx.x * 256 + threadIdx.x;
  if (i >= n4) return;
  const int m = i / (Dd / 4);
  const int d0 = (i % (Dd / 4)) * 4;
  float4 a = ((const float4*)P)[i];
  for (int s = 1; s < S; ++s) {
    float4 p = ((const float4*)P)[(size_t)s * n4 + i];
    a.x += p.x; a.y += p.y; a.z += p.z; a.w += p.w;
  }
  const float* wr = wts + (size_t)m * Ee;
#pragma unroll
  for (int e = 0; e < Ee; ++e) {
    const float w = wr[e];
    float4 b = *(const float4*)(b2 + e * Dd + d0);
    a.x += w * b.x; a.y += w * b.y; a.z += w * b.z; a.w += w * b.w;
  }
  ((float4*)out)[i] = a;
}

// ---------------- stage 2 direct (fallback, round-1 proven) -----------------
__global__ __launch_bounds__(256) void ffn_stage2(
    const bf16* __restrict__ G, const bf16* __restrict__ w2t,
    const float* __restrict__ b2, const float* __restrict__ wts,
    float* __restrict__ out, int e0, int gks, int first) {
  __shared__ __align__(16) bf16 As[128 * 64];
  __shared__ __align__(16) bf16 Bs[128 * 64];
  __shared__ float b2s[Ee][128];
  __shared__ float wls[128][Ee];
  const int mt = blockIdx.x, nt = blockIdx.y;
  const int t = threadIdx.x;
  if (first) {
    for (int i = t; i < Ee * 128; i += 256) {
      const int ee = i >> 7, d = i & 127;
      b2s[ee][d] = b2[ee * Dd + nt * 128 + d];
    }
    for (int i = t; i < 128 * Ee; i += 256) {
      const int r = i >> 3, ee = i & 7;
      wls[r][ee] = wts[((size_t)mt * 128 + r) * Ee + ee];
    }
  }
  f32x4 acc[4][4] = {};
  const bf16* Ag = G + (size_t)mt * 128 * gks;
  const bf16* Bg = w2t + (size_t)nt * 128 * ((size_t)Ee * Hh) + (size_t)e0 * Hh;
  gemm_core(Ag, gks, Bg, (size_t)Ee * Hh, gks / 64, acc, As, Bs);

  const int lane = t & 63, w = t >> 6;
  const int wr = w >> 1, wc = w & 1, fr = lane & 15, fq = lane >> 4;
#pragma unroll
  for (int mi = 0; mi < 4; ++mi)
#pragma unroll
    for (int r = 0; r < 4; ++r) {
      const int lrow = wr * 64 + mi * 16 + fq * 4 + r;
      const size_t m = (size_t)mt * 128 + lrow;
#pragma unroll
      for (int ni = 0; ni < 4; ++ni) {
        const int lcol = wc * 64 + ni * 16 + fr;
        const size_t oidx = m * Dd + nt * 128 + lcol;
        float v = acc[mi][ni][r];
        if (first) {
          float bias = 0.f;
#pragma unroll
          for (int ee = 0; ee < Ee; ++ee) bias += wls[lrow][ee] * b2s[ee][lcol];
          out[oidx] = v + bias;
        } else {
          out[oidx] += v;
        }
      }
    }
}

// ---------------- launch ----------------------------------------------------
extern "C" void kernel_launch(void* const* d_in, const int* in_sizes, int n_in,
                              void* d_out, int out_size, void* d_ws, size_t ws_size,
                              hipStream_t stream) {
  const float* x   = (const float*)d_in[0];
  const float* wts = (const float*)d_in[1];
  const float* w1  = (const float*)d_in[2];
  const float* b1  = (const float*)d_in[3];
  const float* w2  = (const float*)d_in[4];
  const float* b2  = (const float*)d_in[5];
  float* out = (float*)d_out;

  char* ws = (char*)d_ws;
  size_t off = 0;
  bf16* xb  = (bf16*)(ws + off); off += (size_t)Mm * Dd * 2;        // 8 MB
  bf16* w1t = (bf16*)(ws + off); off += (size_t)Ee * Hh * Dd * 2;   // 8 MB
  bf16* w2t = (bf16*)(ws + off); off += (size_t)Dd * Ee * Hh * 2;   // 8 MB

  const size_t gfull = (size_t)Mm * Ee * Hh * 2;  // 134 MB (all-expert G)
  const size_t psz   = (size_t)Mm * Dd * 4;       // 16.8 MB per split-K partial

  cvt_x_kernel<<<(Mm * Dd / 4 + 255) / 256, 256, 0, stream>>>(x, xb, Mm * Dd / 4);
  transpose_cvt<<<dim3(Hh / 64, Dd / 64, Ee), 256, 0, stream>>>(
      w1, w1t, Dd, Hh, (size_t)Dd * Hh, (size_t)Hh * Dd, Dd);
  transpose_cvt<<<dim3(Dd / 64, Hh / 64, Ee), 256, 0, stream>>>(
      w2, w2t, Hh, Dd, (size_t)Hh * Dd, (size_t)Hh, Ee * Hh);

  // pick split-K factor by available workspace
  int S = 0;
  if (ws_size >= off + gfull + 4 * psz) S = 4;
  else if (ws_size >= off + gfull + 2 * psz) S = 2;
  else if (ws_size >= off + gfull) S = 1;

  if (S >= 2) {
    bf16* G = (bf16*)(ws + off);
    float* P = (float*)(ws + off + gfull);
    const int gks = Ee * Hh;  // 8192
    ffn_stage1<<<dim3(Mm / 128, Hh / 128, Ee), 256, 0, stream>>>(
        xb, w1t, b1, wts, G, 0, gks);
    ffn_stage2_partial<<<dim3(Mm / 128, Dd / 128, S), 256, 0, stream>>>(
        G, w2t, P, gks, gks / S);
    reduce_bias<<<(Mm * Dd / 4 + 255) / 256, 256, 0, stream>>>(P, wts, b2, out, S);
  } else {
    // fallback: chunked direct path (round-1 proven)
    bf16* G = (bf16*)(ws + off);
    size_t avail = ws_size > off ? ws_size - off : 0;
    size_t slab = (size_t)Mm * Hh * 2;
    int Ec = (int)(avail / slab);
    if (Ec < 1) Ec = 1;
    if (Ec > Ee) Ec = Ee;
    int first = 1;
    for (int e0 = 0; e0 < Ee;) {
      const int ec = (Ee - e0 < Ec) ? (Ee - e0) : Ec;
      const int gks = ec * Hh;
      ffn_stage1<<<dim3(Mm / 128, Hh / 128, ec), 256, 0, stream>>>(
          xb, w1t, b1, wts, G, e0, gks);
      ffn_stage2<<<dim3(Mm / 128, Dd / 128), 256, 0, stream>>>(
          G, w2t, b2, wts, out, e0, gks, first);
      e0 += ec;
      first = 0;
    }
  }
}

// Round 3
// 240.033 us; speedup vs baseline: 1.1461x; 1.0530x over previous
//
#include <hip/hip_runtime.h>
#include <hip/hip_bf16.h>

#define DEV __device__ __forceinline__

typedef __bf16 bf16;
typedef __bf16 bf16x4 __attribute__((ext_vector_type(4)));
typedef __bf16 bf16x8 __attribute__((ext_vector_type(8)));
typedef float f32x4 __attribute__((ext_vector_type(4)));

static constexpr int Bb = 4, Ll = 2048, Dd = 512, Ee = 8, Hh = 1024;
static constexpr int Mm = Bb * Ll;  // 8192 tokens
static constexpr int GKS = Ee * Hh; // 8192, G row stride (split-K path)

// ---------------- async global->LDS (16B per lane, wave-uniform LDS base) ---
DEV void gload_lds16(const void* g, void* l) {
  __builtin_amdgcn_global_load_lds(
      (const __attribute__((address_space(1))) unsigned int*)g,
      (__attribute__((address_space(3))) unsigned int*)l, 16, 0, 0);
}

// fast exact-enough gelu: tanh form, g = h - h/(exp(2y)+1)
DEV float gelu_fast(float h) {
  const float k = 0.7978845608028654f * 2.0f * 1.4426950408889634f;
  float h2 = h * h;
  float y = h * (k + (0.044715f * k) * h2);
  float t = exp2f(y);
  return h - h * __frcp_rn(t + 1.0f);
}

// ---------------- elementwise f32 -> bf16 -----------------------------------
__global__ void cvt_x_kernel(const float* __restrict__ in, bf16* __restrict__ out, int n4) {
  int i = blockIdx.x * blockDim.x + threadIdx.x;
  if (i < n4) {
    float4 v = ((const float4*)in)[i];
    bf16x4 o = {(bf16)v.x, (bf16)v.y, (bf16)v.z, (bf16)v.w};
    ((bf16x4*)out)[i] = o;
  }
}

// ---------------- tiled transpose + convert ---------------------------------
__global__ void transpose_cvt(const float* __restrict__ in, bf16* __restrict__ out,
                              int R, int C, size_t in_es, size_t out_es, int out_rs) {
  __shared__ float tile[64][65];
  const int e = blockIdx.z;
  const float* ip = in + (size_t)e * in_es;
  bf16* op = out + (size_t)e * out_es;
  const int r0 = blockIdx.y * 64, c0 = blockIdx.x * 64;
  const int tc = threadIdx.x & 63, tr = threadIdx.x >> 6;
#pragma unroll
  for (int i = 0; i < 16; ++i) {
    const int r = tr + i * 4;
    tile[r][tc] = ip[(size_t)(r0 + r) * C + c0 + tc];
  }
  __syncthreads();
  const int wr = threadIdx.x & 63, wc0 = threadIdx.x >> 6;
#pragma unroll
  for (int i = 0; i < 16; ++i) {
    const int c = wc0 + i * 4;
    op[(size_t)(c0 + c) * out_rs + r0 + wr] = (bf16)tile[wr][c];
  }
}

// ---------------- 128x128 bf16 MFMA GEMM core (BK=64) -----------------------
// Compile-time row strides ARS/BRS (elements). XOR-swizzled LDS (free 2-way).
template <int ARS, int BRS>
DEV void gemm_core(const bf16* __restrict__ Ag, const bf16* __restrict__ Bg,
                   int ksteps, f32x4 (&acc)[4][4], bf16* As, bf16* Bs) {
  const int t = threadIdx.x;
  const int lane = t & 63;
  const int w = t >> 6;
  const int srow = t >> 3;
  const int sseg = t & 7;
  const int wr = w >> 1, wc = w & 1;
  const int fr = lane & 15;
  const int fg = lane >> 4;

  for (int s = 0; s < ksteps; ++s) {
    __syncthreads();
#pragma unroll
    for (int i = 0; i < 4; ++i) {
      const int row = i * 32 + srow;
      const int q = sseg ^ (row & 7);
      gload_lds16(Ag + (size_t)row * ARS + s * 64 + q * 8,
                  (char*)As + i * 4096 + w * 1024);
      gload_lds16(Bg + (size_t)row * BRS + s * 64 + q * 8,
                  (char*)Bs + i * 4096 + w * 1024);
    }
    __syncthreads();
#pragma unroll
    for (int kk = 0; kk < 2; ++kk) {
      bf16x8 af[4], bfr[4];
#pragma unroll
      for (int mi = 0; mi < 4; ++mi) {
        const int row = wr * 64 + mi * 16 + fr;
        const int q = (kk * 4 + fg) ^ (row & 7);
        af[mi] = *(const bf16x8*)((const char*)As + row * 128 + q * 16);
      }
#pragma unroll
      for (int ni = 0; ni < 4; ++ni) {
        const int row = wc * 64 + ni * 16 + fr;
        const int q = (kk * 4 + fg) ^ (row & 7);
        bfr[ni] = *(const bf16x8*)((const char*)Bs + row * 128 + q * 16);
      }
#pragma unroll
      for (int mi = 0; mi < 4; ++mi)
#pragma unroll
        for (int ni = 0; ni < 4; ++ni)
          acc[mi][ni] = __builtin_amdgcn_mfma_f32_16x16x32_bf16(
              af[mi], bfr[ni], acc[mi][ni], 0, 0, 0);
    }
  }
}

// runtime-stride variant (fallback path only)
DEV void gemm_core_r(const bf16* __restrict__ Ag, size_t a_rs,
                     const bf16* __restrict__ Bg, size_t b_rs,
                     int ksteps, f32x4 (&acc)[4][4], bf16* As, bf16* Bs) {
  const int t = threadIdx.x;
  const int lane = t & 63;
  const int w = t >> 6;
  const int srow = t >> 3;
  const int sseg = t & 7;
  const int wr = w >> 1, wc = w & 1;
  const int fr = lane & 15;
  const int fg = lane >> 4;
  for (int s = 0; s < ksteps; ++s) {
    __syncthreads();
#pragma unroll
    for (int i = 0; i < 4; ++i) {
      const int row = i * 32 + srow;
      const int q = sseg ^ (row & 7);
      gload_lds16(Ag + (size_t)row * a_rs + s * 64 + q * 8,
                  (char*)As + i * 4096 + w * 1024);
      gload_lds16(Bg + (size_t)row * b_rs + s * 64 + q * 8,
                  (char*)Bs + i * 4096 + w * 1024);
    }
    __syncthreads();
#pragma unroll
    for (int kk = 0; kk < 2; ++kk) {
      bf16x8 af[4], bfr[4];
#pragma unroll
      for (int mi = 0; mi < 4; ++mi) {
        const int row = wr * 64 + mi * 16 + fr;
        const int q = (kk * 4 + fg) ^ (row & 7);
        af[mi] = *(const bf16x8*)((const char*)As + row * 128 + q * 16);
      }
#pragma unroll
      for (int ni = 0; ni < 4; ++ni) {
        const int row = wc * 64 + ni * 16 + fr;
        const int q = (kk * 4 + fg) ^ (row & 7);
        bfr[ni] = *(const bf16x8*)((const char*)Bs + row * 128 + q * 16);
      }
#pragma unroll
      for (int mi = 0; mi < 4; ++mi)
#pragma unroll
        for (int ni = 0; ni < 4; ++ni)
          acc[mi][ni] = __builtin_amdgcn_mfma_f32_16x16x32_bf16(
              af[mi], bfr[ni], acc[mi][ni], 0, 0, 0);
    }
  }
}

// ---------------- stage 1 (split-K path, compile-time strides) --------------
__global__ __launch_bounds__(256) void ffn_stage1_t(
    const bf16* __restrict__ xb, const bf16* __restrict__ w1t,
    const float* __restrict__ b1, const float* __restrict__ wts,
    bf16* __restrict__ G) {
  __shared__ __align__(16) bf16 As[128 * 64];
  __shared__ __align__(16) bf16 Bs[128 * 64];
  __shared__ float b1s[128];
  __shared__ float wls[128];
  const int mt = blockIdx.x, ht = blockIdx.y, e = blockIdx.z;
  const int t = threadIdx.x;
  if (t < 128) b1s[t] = b1[e * Hh + ht * 128 + t];
  else wls[t - 128] = wts[((size_t)mt * 128 + (t - 128)) * Ee + e];

  f32x4 acc[4][4] = {};
  const bf16* Ag = xb + (size_t)mt * 128 * Dd;
  const bf16* Bg = w1t + ((size_t)e * Hh + (size_t)ht * 128) * Dd;
  gemm_core<Dd, Dd>(Ag, Bg, Dd / 64, acc, As, Bs);  // barriers inside fence b1s/wls

  const int lane = t & 63, w = t >> 6;
  const int wr = w >> 1, wc = w & 1, fr = lane & 15, fq = lane >> 4;
  float bcol[4];
#pragma unroll
  for (int ni = 0; ni < 4; ++ni) bcol[ni] = b1s[wc * 64 + ni * 16 + fr];
  bf16* gp = G + ((size_t)mt * 128 + wr * 64 + fq * 4) * GKS
               + (size_t)e * Hh + ht * 128 + wc * 64 + fr;
#pragma unroll
  for (int mi = 0; mi < 4; ++mi) {
#pragma unroll
    for (int r = 0; r < 4; ++r) {
      const float wgt = wls[wr * 64 + mi * 16 + fq * 4 + r];
#pragma unroll
      for (int ni = 0; ni < 4; ++ni) {
        float v = acc[mi][ni][r] + bcol[ni];
        gp[(size_t)(mi * 16 + r) * GKS + ni * 16] = (bf16)(gelu_fast(v) * wgt);
      }
    }
  }
}

// ---------------- stage 2 split-K partial -----------------------------------
__global__ __launch_bounds__(256) void ffn_stage2_partial(
    const bf16* __restrict__ G, const bf16* __restrict__ w2t,
    float* __restrict__ P, int kchunk) {
  __shared__ __align__(16) bf16 As[128 * 64];
  __shared__ __align__(16) bf16 Bs[128 * 64];
  const int mt = blockIdx.x, nt = blockIdx.y, s = blockIdx.z;
  f32x4 acc[4][4] = {};
  const bf16* Ag = G + (size_t)mt * 128 * GKS + (size_t)s * kchunk;
  const bf16* Bg = w2t + (size_t)nt * 128 * GKS + (size_t)s * kchunk;
  gemm_core<GKS, GKS>(Ag, Bg, kchunk / 64, acc, As, Bs);

  float* Pp = P + (size_t)s * Mm * Dd;
  const int t = threadIdx.x;
  const int lane = t & 63, w = t >> 6;
  const int wr = w >> 1, wc = w & 1, fr = lane & 15, fq = lane >> 4;
#pragma unroll
  for (int mi = 0; mi < 4; ++mi)
#pragma unroll
    for (int r = 0; r < 4; ++r) {
      const size_t m = (size_t)mt * 128 + wr * 64 + mi * 16 + fq * 4 + r;
#pragma unroll
      for (int ni = 0; ni < 4; ++ni) {
        const int d = nt * 128 + wc * 64 + ni * 16 + fr;
        Pp[m * Dd + d] = acc[mi][ni][r];
      }
    }
}

// ---------------- reduce partials + bias ------------------------------------
__global__ __launch_bounds__(256) void reduce_bias(
    const float* __restrict__ P, const float* __restrict__ wts,
    const float* __restrict__ b2, float* __restrict__ out, int S) {
  const int n4 = Mm * Dd / 4;
  int i = blockIdx.x * 256 + threadIdx.x;
  if (i >= n4) return;
  const int m = i / (Dd / 4);
  const int d0 = (i % (Dd / 4)) * 4;
  float4 a = ((const float4*)P)[i];
  for (int s = 1; s < S; ++s) {
    float4 p = ((const float4*)P)[(size_t)s * n4 + i];
    a.x += p.x; a.y += p.y; a.z += p.z; a.w += p.w;
  }
  const float* wr = wts + (size_t)m * Ee;
#pragma unroll
  for (int e = 0; e < Ee; ++e) {
    const float w = wr[e];
    float4 b = *(const float4*)(b2 + e * Dd + d0);
    a.x += w * b.x; a.y += w * b.y; a.z += w * b.z; a.w += w * b.w;
  }
  ((float4*)out)[i] = a;
}

// ---------------- fallback path (runtime strides, round-1 proven) -----------
__global__ __launch_bounds__(256) void ffn_stage1(
    const bf16* __restrict__ xb, const bf16* __restrict__ w1t,
    const float* __restrict__ b1, const float* __restrict__ wts,
    bf16* __restrict__ G, int e0, int gks) {
  __shared__ __align__(16) bf16 As[128 * 64];
  __shared__ __align__(16) bf16 Bs[128 * 64];
  const int mt = blockIdx.x, ht = blockIdx.y, le = blockIdx.z;
  const int e = e0 + le;
  f32x4 acc[4][4] = {};
  const bf16* Ag = xb + (size_t)mt * 128 * Dd;
  const bf16* Bg = w1t + ((size_t)e * Hh + (size_t)ht * 128) * Dd;
  gemm_core_r(Ag, Dd, Bg, Dd, Dd / 64, acc, As, Bs);
  const int t = threadIdx.x;
  const int lane = t & 63, w = t >> 6;
  const int wr = w >> 1, wc = w & 1, fr = lane & 15, fq = lane >> 4;
#pragma unroll
  for (int mi = 0; mi < 4; ++mi)
#pragma unroll
    for (int r = 0; r < 4; ++r) {
      const int m = mt * 128 + wr * 64 + mi * 16 + fq * 4 + r;
      const float wgt = wts[(size_t)m * Ee + e];
#pragma unroll
      for (int ni = 0; ni < 4; ++ni) {
        const int h = ht * 128 + wc * 64 + ni * 16 + fr;
        float v = acc[mi][ni][r] + b1[e * Hh + h];
        G[(size_t)m * gks + (size_t)le * Hh + h] = (bf16)(gelu_fast(v) * wgt);
      }
    }
}

__global__ __launch_bounds__(256) void ffn_stage2(
    const bf16* __restrict__ G, const bf16* __restrict__ w2t,
    const float* __restrict__ b2, const float* __restrict__ wts,
    float* __restrict__ out, int e0, int gks, int first) {
  __shared__ __align__(16) bf16 As[128 * 64];
  __shared__ __align__(16) bf16 Bs[128 * 64];
  __shared__ float b2s[Ee][128];
  __shared__ float wls[128][Ee];
  const int mt = blockIdx.x, nt = blockIdx.y;
  const int t = threadIdx.x;
  if (first) {
    for (int i = t; i < Ee * 128; i += 256) {
      const int ee = i >> 7, d = i & 127;
      b2s[ee][d] = b2[ee * Dd + nt * 128 + d];
    }
    for (int i = t; i < 128 * Ee; i += 256) {
      const int r = i >> 3, ee = i & 7;
      wls[r][ee] = wts[((size_t)mt * 128 + r) * Ee + ee];
    }
  }
  f32x4 acc[4][4] = {};
  const bf16* Ag = G + (size_t)mt * 128 * gks;
  const bf16* Bg = w2t + (size_t)nt * 128 * ((size_t)Ee * Hh) + (size_t)e0 * Hh;
  gemm_core_r(Ag, gks, Bg, (size_t)Ee * Hh, gks / 64, acc, As, Bs);
  const int lane = t & 63, w = t >> 6;
  const int wr = w >> 1, wc = w & 1, fr = lane & 15, fq = lane >> 4;
#pragma unroll
  for (int mi = 0; mi < 4; ++mi)
#pragma unroll
    for (int r = 0; r < 4; ++r) {
      const int lrow = wr * 64 + mi * 16 + fq * 4 + r;
      const size_t m = (size_t)mt * 128 + lrow;
#pragma unroll
      for (int ni = 0; ni < 4; ++ni) {
        const int lcol = wc * 64 + ni * 16 + fr;
        const size_t oidx = m * Dd + nt * 128 + lcol;
        float v = acc[mi][ni][r];
        if (first) {
          float bias = 0.f;
#pragma unroll
          for (int ee = 0; ee < Ee; ++ee) bias += wls[lrow][ee] * b2s[ee][lcol];
          out[oidx] = v + bias;
        } else {
          out[oidx] += v;
        }
      }
    }
}

// ---------------- launch ----------------------------------------------------
extern "C" void kernel_launch(void* const* d_in, const int* in_sizes, int n_in,
                              void* d_out, int out_size, void* d_ws, size_t ws_size,
                              hipStream_t stream) {
  const float* x   = (const float*)d_in[0];
  const float* wts = (const float*)d_in[1];
  const float* w1  = (const float*)d_in[2];
  const float* b1  = (const float*)d_in[3];
  const float* w2  = (const float*)d_in[4];
  const float* b2  = (const float*)d_in[5];
  float* out = (float*)d_out;

  char* ws = (char*)d_ws;
  size_t off = 0;
  bf16* xb  = (bf16*)(ws + off); off += (size_t)Mm * Dd * 2;
  bf16* w1t = (bf16*)(ws + off); off += (size_t)Ee * Hh * Dd * 2;
  bf16* w2t = (bf16*)(ws + off); off += (size_t)Dd * Ee * Hh * 2;

  const size_t gfull = (size_t)Mm * Ee * Hh * 2;  // 134 MB
  const size_t psz   = (size_t)Mm * Dd * 4;       // 16.8 MB

  cvt_x_kernel<<<(Mm * Dd / 4 + 255) / 256, 256, 0, stream>>>(x, xb, Mm * Dd / 4);
  transpose_cvt<<<dim3(Hh / 64, Dd / 64, Ee), 256, 0, stream>>>(
      w1, w1t, Dd, Hh, (size_t)Dd * Hh, (size_t)Hh * Dd, Dd);
  transpose_cvt<<<dim3(Dd / 64, Hh / 64, Ee), 256, 0, stream>>>(
      w2, w2t, Hh, Dd, (size_t)Hh * Dd, (size_t)Hh, Ee * Hh);

  int S = 0;
  if (ws_size >= off + gfull + 4 * psz) S = 4;
  else if (ws_size >= off + gfull + 2 * psz) S = 2;

  if (S >= 2) {
    bf16* G = (bf16*)(ws + off);
    float* P = (float*)(ws + off + gfull);
    ffn_stage1_t<<<dim3(Mm / 128, Hh / 128, Ee), 256, 0, stream>>>(
        xb, w1t, b1, wts, G);
    ffn_stage2_partial<<<dim3(Mm / 128, Dd / 128, S), 256, 0, stream>>>(
        G, w2t, P, GKS / S);
    reduce_bias<<<(Mm * Dd / 4 + 255) / 256, 256, 0, stream>>>(P, wts, b2, out, S);
  } else {
    bf16* G = (bf16*)(ws + off);
    size_t avail = ws_size > off ? ws_size - off : 0;
    size_t slab = (size_t)Mm * Hh * 2;
    int Ec = (int)(avail / slab);
    if (Ec < 1) Ec = 1;
    if (Ec > Ee) Ec = Ee;
    int first = 1;
    for (int e0 = 0; e0 < Ee;) {
      const int ec = (Ee - e0 < Ec) ? (Ee - e0) : Ec;
      const int gks = ec * Hh;
      ffn_stage1<<<dim3(Mm / 128, Hh / 128, ec), 256, 0, stream>>>(
          xb, w1t, b1, wts, G, e0, gks);
      ffn_stage2<<<dim3(Mm / 128, Dd / 128), 256, 0, stream>>>(
          G, w2t, b2, wts, out, e0, gks, first);
      e0 += ec;
      first = 0;
    }
  }
}

// Round 4
// 220.948 us; speedup vs baseline: 1.2451x; 1.0864x over previous
//
#include <hip/hip_runtime.h>
#include <hip/hip_bf16.h>

#define DEV __device__ __forceinline__

typedef __bf16 bf16;
typedef __bf16 bf16x4 __attribute__((ext_vector_type(4)));
typedef __bf16 bf16x8 __attribute__((ext_vector_type(8)));
typedef float f32x4 __attribute__((ext_vector_type(4)));

static constexpr int Bb = 4, Ll = 2048, Dd = 512, Ee = 8, Hh = 1024;
static constexpr int Mm = Bb * Ll;  // 8192 tokens
static constexpr int GKS = Ee * Hh; // 8192, G row stride

// ---------------- async global->LDS (16B per lane, wave-uniform LDS base) ---
DEV void gload_lds16(const void* g, void* l) {
  __builtin_amdgcn_global_load_lds(
      (const __attribute__((address_space(1))) unsigned int*)g,
      (__attribute__((address_space(3))) unsigned int*)l, 16, 0, 0);
}

// fast exact-enough gelu: tanh form, g = h - h/(exp(2y)+1)
DEV float gelu_fast(float h) {
  const float k = 0.7978845608028654f * 2.0f * 1.4426950408889634f;
  float h2 = h * h;
  float y = h * (k + (0.044715f * k) * h2);
  float t = exp2f(y);
  return h - h * __frcp_rn(t + 1.0f);
}

// ---------------- elementwise f32 -> bf16 -----------------------------------
__global__ void cvt_x_kernel(const float* __restrict__ in, bf16* __restrict__ out, int n4) {
  int i = blockIdx.x * blockDim.x + threadIdx.x;
  if (i < n4) {
    float4 v = ((const float4*)in)[i];
    bf16x4 o = {(bf16)v.x, (bf16)v.y, (bf16)v.z, (bf16)v.w};
    ((bf16x4*)out)[i] = o;
  }
}

// ---------------- tiled transpose + convert ---------------------------------
__global__ void transpose_cvt(const float* __restrict__ in, bf16* __restrict__ out,
                              int R, int C, size_t in_es, size_t out_es, int out_rs) {
  __shared__ float tile[64][65];
  const int e = blockIdx.z;
  const float* ip = in + (size_t)e * in_es;
  bf16* op = out + (size_t)e * out_es;
  const int r0 = blockIdx.y * 64, c0 = blockIdx.x * 64;
  const int tc = threadIdx.x & 63, tr = threadIdx.x >> 6;
#pragma unroll
  for (int i = 0; i < 16; ++i) {
    const int r = tr + i * 4;
    tile[r][tc] = ip[(size_t)(r0 + r) * C + c0 + tc];
  }
  __syncthreads();
  const int wr = threadIdx.x & 63, wc0 = threadIdx.x >> 6;
#pragma unroll
  for (int i = 0; i < 16; ++i) {
    const int c = wc0 + i * 4;
    op[(size_t)(c0 + c) * out_rs + r0 + wr] = (bf16)tile[wr][c];
  }
}

// ============ 256x256 8-phase deep-pipelined GEMM core (BK=64) ==============
// 512 threads = 8 waves (2M x 4N). LDS: 2 bufs x (A 32KB + B 32KB) = 128KB.
// XOR swizzle: seg' = seg ^ (row&7). Staging: 8 gload_lds per K-tile per wave,
// issued at iter top for kt+1; counted s_waitcnt vmcnt(8) keeps them in flight
// across barriers (T4). 4 MFMA phases per K-tile, setprio around MFMA (T5).
// MFMA operands SWAPPED: D col(lane&15)=A-row-dim(m), D row(fq*4+r)=B-row-dim.
template <int ARS, int BRS>
DEV void gemm256_core(const bf16* __restrict__ Ag, const bf16* __restrict__ Bg,
                      int nt, f32x4 (&acc)[8][4], char* lds) {
  const int t = threadIdx.x;
  const int lane = t & 63;
  const int wid = t >> 6;          // 0..7
  const int wm = wid >> 2, wn = wid & 3;
  const int fr = lane & 15, fg = lane >> 4;
  const int srow = t >> 3;         // 0..63
  const int sseg = t & 7;

  auto stage = [&](int kt, int p) {
    char* As = lds + p * 65536;
    char* Bs = lds + p * 65536 + 32768;
#pragma unroll
    for (int i = 0; i < 4; ++i) {
      const int row = i * 64 + srow;
      const int q = sseg ^ (row & 7);
      gload_lds16(Ag + (size_t)row * ARS + kt * 64 + q * 8, As + i * 8192 + wid * 1024);
      gload_lds16(Bg + (size_t)row * BRS + kt * 64 + q * 8, Bs + i * 8192 + wid * 1024);
    }
  };

  stage(0, 0);
  for (int kt = 0; kt < nt; ++kt) {
    const int p = kt & 1;
    if (kt + 1 < nt) {
      stage(kt + 1, p ^ 1);
      asm volatile("s_waitcnt vmcnt(8)" ::: "memory");  // kt's 8 landed, kt+1's fly
    } else {
      asm volatile("s_waitcnt vmcnt(0)" ::: "memory");
    }
    __builtin_amdgcn_s_barrier();  // all waves' staging of buf p visible
    const char* As = lds + p * 65536;
    const char* Bs = lds + p * 65536 + 32768;
    bf16x8 bfrag[4][2];
#pragma unroll
    for (int q = 0; q < 4; ++q) {
      if (q == 0) {
#pragma unroll
        for (int fj = 0; fj < 4; ++fj)
#pragma unroll
          for (int kk = 0; kk < 2; ++kk) {
            const int row = wn * 64 + fj * 16 + fr;
            const int seg = (kk * 4 + fg) ^ (row & 7);
            bfrag[fj][kk] = *(const bf16x8*)(Bs + row * 128 + seg * 16);
          }
      }
      bf16x8 af[2][2];
#pragma unroll
      for (int fil = 0; fil < 2; ++fil)
#pragma unroll
        for (int kk = 0; kk < 2; ++kk) {
          const int row = wm * 128 + (q * 2 + fil) * 16 + fr;
          const int seg = (kk * 4 + fg) ^ (row & 7);
          af[fil][kk] = *(const bf16x8*)(As + row * 128 + seg * 16);
        }
      __builtin_amdgcn_s_barrier();
      asm volatile("s_waitcnt lgkmcnt(0)" ::: "memory");
      __builtin_amdgcn_sched_barrier(0);
      __builtin_amdgcn_s_setprio(1);
#pragma unroll
      for (int fil = 0; fil < 2; ++fil)
#pragma unroll
        for (int fj = 0; fj < 4; ++fj)
#pragma unroll
          for (int kk = 0; kk < 2; ++kk)
            acc[q * 2 + fil][fj] = __builtin_amdgcn_mfma_f32_16x16x32_bf16(
                bfrag[fj][kk], af[fil][kk], acc[q * 2 + fil][fj], 0, 0, 0);
      __builtin_amdgcn_s_setprio(0);
      __builtin_amdgcn_s_barrier();
    }
  }
}

// ---------------- stage 1 (256^2): g = w[m,e]*gelu(x@W1_e + b1_e) -----------
__global__ __launch_bounds__(512, 2) void ffn_stage1_256(
    const bf16* __restrict__ xb, const bf16* __restrict__ w1t,
    const float* __restrict__ b1, const float* __restrict__ wts,
    bf16* __restrict__ G) {
  __shared__ __align__(16) char lds[131072];
  __shared__ float b1s[256];
  __shared__ float wls[256];
  const int mt = blockIdx.x;
  const int e = blockIdx.y >> 2, ht2 = blockIdx.y & 3;
  const int t = threadIdx.x;
  if (t < 256) b1s[t] = b1[e * Hh + ht2 * 256 + t];
  else wls[t - 256] = wts[((size_t)mt * 256 + (t - 256)) * Ee + e];

  f32x4 acc[8][4] = {};
  const bf16* Ag = xb + (size_t)mt * 256 * Dd;
  const bf16* Bg = w1t + ((size_t)e * Hh + (size_t)ht2 * 256) * Dd;
  gemm256_core<Dd, Dd>(Ag, Bg, Dd / 64, acc, lds);

  const int lane = t & 63, wid = t >> 6;
  const int wm = wid >> 2, wn = wid & 3;
  const int fr = lane & 15, fq = lane >> 4;
  float b1v[4][4];
#pragma unroll
  for (int fj = 0; fj < 4; ++fj)
#pragma unroll
    for (int r = 0; r < 4; ++r) b1v[fj][r] = b1s[wn * 64 + fj * 16 + fq * 4 + r];
#pragma unroll
  for (int fi = 0; fi < 8; ++fi) {
    const int m = mt * 256 + wm * 128 + fi * 16 + fr;
    const float wgt = wls[wm * 128 + fi * 16 + fr];
    bf16* gp = G + (size_t)m * GKS + e * Hh + ht2 * 256 + wn * 64 + fq * 4;
#pragma unroll
    for (int fj = 0; fj < 4; ++fj) {
      bf16x4 o;
#pragma unroll
      for (int r = 0; r < 4; ++r) {
        float v = acc[fi][fj][r] + b1v[fj][r];
        o[r] = (bf16)(gelu_fast(v) * wgt);
      }
      *(bf16x4*)(gp + fj * 16) = o;
    }
  }
}

// ---------------- stage 2 (256^2) split-K partial ---------------------------
__global__ __launch_bounds__(512, 2) void ffn_stage2_256(
    const bf16* __restrict__ G, const bf16* __restrict__ w2t,
    float* __restrict__ P, int kchunk) {
  __shared__ __align__(16) char lds[131072];
  const int mt = blockIdx.x, nt = blockIdx.y, s = blockIdx.z;
  f32x4 acc[8][4] = {};
  const bf16* Ag = G + (size_t)mt * 256 * GKS + (size_t)s * kchunk;
  const bf16* Bg = w2t + (size_t)nt * 256 * GKS + (size_t)s * kchunk;
  gemm256_core<GKS, GKS>(Ag, Bg, kchunk / 64, acc, lds);

  float* Pp = P + (size_t)s * Mm * Dd;
  const int t = threadIdx.x;
  const int lane = t & 63, wid = t >> 6;
  const int wm = wid >> 2, wn = wid & 3;
  const int fr = lane & 15, fq = lane >> 4;
#pragma unroll
  for (int fi = 0; fi < 8; ++fi) {
    const size_t m = (size_t)mt * 256 + wm * 128 + fi * 16 + fr;
    float* pp = Pp + m * Dd + nt * 256 + wn * 64 + fq * 4;
#pragma unroll
    for (int fj = 0; fj < 4; ++fj) *(f32x4*)(pp + fj * 16) = acc[fi][fj];
  }
}

// ---------------- reduce partials + bias ------------------------------------
__global__ __launch_bounds__(256) void reduce_bias(
    const float* __restrict__ P, const float* __restrict__ wts,
    const float* __restrict__ b2, float* __restrict__ out, int S) {
  const int n4 = Mm * Dd / 4;
  int i = blockIdx.x * 256 + threadIdx.x;
  if (i >= n4) return;
  const int m = i / (Dd / 4);
  const int d0 = (i % (Dd / 4)) * 4;
  float4 a = ((const float4*)P)[i];
  for (int s = 1; s < S; ++s) {
    float4 p = ((const float4*)P)[(size_t)s * n4 + i];
    a.x += p.x; a.y += p.y; a.z += p.z; a.w += p.w;
  }
  const float* wr = wts + (size_t)m * Ee;
#pragma unroll
  for (int e = 0; e < Ee; ++e) {
    const float w = wr[e];
    float4 b = *(const float4*)(b2 + e * Dd + d0);
    a.x += w * b.x; a.y += w * b.y; a.z += w * b.z; a.w += w * b.w;
  }
  ((float4*)out)[i] = a;
}

// ============ fallback: 128^2 m97-structure path (R3 proven) ================
template <int ARS, int BRS>
DEV void gemm_core(const bf16* __restrict__ Ag, const bf16* __restrict__ Bg,
                   int ksteps, f32x4 (&acc)[4][4], bf16* As, bf16* Bs) {
  const int t = threadIdx.x;
  const int lane = t & 63;
  const int w = t >> 6;
  const int srow = t >> 3;
  const int sseg = t & 7;
  const int wr = w >> 1, wc = w & 1;
  const int fr = lane & 15;
  const int fg = lane >> 4;
  for (int s = 0; s < ksteps; ++s) {
    __syncthreads();
#pragma unroll
    for (int i = 0; i < 4; ++i) {
      const int row = i * 32 + srow;
      const int q = sseg ^ (row & 7);
      gload_lds16(Ag + (size_t)row * ARS + s * 64 + q * 8,
                  (char*)As + i * 4096 + w * 1024);
      gload_lds16(Bg + (size_t)row * BRS + s * 64 + q * 8,
                  (char*)Bs + i * 4096 + w * 1024);
    }
    __syncthreads();
#pragma unroll
    for (int kk = 0; kk < 2; ++kk) {
      bf16x8 af[4], bfr[4];
#pragma unroll
      for (int mi = 0; mi < 4; ++mi) {
        const int row = wr * 64 + mi * 16 + fr;
        const int q = (kk * 4 + fg) ^ (row & 7);
        af[mi] = *(const bf16x8*)((const char*)As + row * 128 + q * 16);
      }
#pragma unroll
      for (int ni = 0; ni < 4; ++ni) {
        const int row = wc * 64 + ni * 16 + fr;
        const int q = (kk * 4 + fg) ^ (row & 7);
        bfr[ni] = *(const bf16x8*)((const char*)Bs + row * 128 + q * 16);
      }
#pragma unroll
      for (int mi = 0; mi < 4; ++mi)
#pragma unroll
        for (int ni = 0; ni < 4; ++ni)
          acc[mi][ni] = __builtin_amdgcn_mfma_f32_16x16x32_bf16(
              af[mi], bfr[ni], acc[mi][ni], 0, 0, 0);
    }
  }
}

__global__ __launch_bounds__(256) void ffn_stage1_t(
    const bf16* __restrict__ xb, const bf16* __restrict__ w1t,
    const float* __restrict__ b1, const float* __restrict__ wts,
    bf16* __restrict__ G) {
  __shared__ __align__(16) bf16 As[128 * 64];
  __shared__ __align__(16) bf16 Bs[128 * 64];
  __shared__ float b1s[128];
  __shared__ float wls[128];
  const int mt = blockIdx.x, ht = blockIdx.y, e = blockIdx.z;
  const int t = threadIdx.x;
  if (t < 128) b1s[t] = b1[e * Hh + ht * 128 + t];
  else wls[t - 128] = wts[((size_t)mt * 128 + (t - 128)) * Ee + e];
  f32x4 acc[4][4] = {};
  const bf16* Ag = xb + (size_t)mt * 128 * Dd;
  const bf16* Bg = w1t + ((size_t)e * Hh + (size_t)ht * 128) * Dd;
  gemm_core<Dd, Dd>(Ag, Bg, Dd / 64, acc, As, Bs);
  const int lane = t & 63, w = t >> 6;
  const int wr = w >> 1, wc = w & 1, fr = lane & 15, fq = lane >> 4;
  float bcol[4];
#pragma unroll
  for (int ni = 0; ni < 4; ++ni) bcol[ni] = b1s[wc * 64 + ni * 16 + fr];
  bf16* gp = G + ((size_t)mt * 128 + wr * 64 + fq * 4) * GKS
               + (size_t)e * Hh + ht * 128 + wc * 64 + fr;
#pragma unroll
  for (int mi = 0; mi < 4; ++mi)
#pragma unroll
    for (int r = 0; r < 4; ++r) {
      const float wgt = wls[wr * 64 + mi * 16 + fq * 4 + r];
#pragma unroll
      for (int ni = 0; ni < 4; ++ni) {
        float v = acc[mi][ni][r] + bcol[ni];
        gp[(size_t)(mi * 16 + r) * GKS + ni * 16] = (bf16)(gelu_fast(v) * wgt);
      }
    }
}

__global__ __launch_bounds__(256) void ffn_stage2_partial(
    const bf16* __restrict__ G, const bf16* __restrict__ w2t,
    float* __restrict__ P, int kchunk) {
  __shared__ __align__(16) bf16 As[128 * 64];
  __shared__ __align__(16) bf16 Bs[128 * 64];
  const int mt = blockIdx.x, nt = blockIdx.y, s = blockIdx.z;
  f32x4 acc[4][4] = {};
  const bf16* Ag = G + (size_t)mt * 128 * GKS + (size_t)s * kchunk;
  const bf16* Bg = w2t + (size_t)nt * 128 * GKS + (size_t)s * kchunk;
  gemm_core<GKS, GKS>(Ag, Bg, kchunk / 64, acc, As, Bs);
  float* Pp = P + (size_t)s * Mm * Dd;
  const int t = threadIdx.x;
  const int lane = t & 63, w = t >> 6;
  const int wr = w >> 1, wc = w & 1, fr = lane & 15, fq = lane >> 4;
#pragma unroll
  for (int mi = 0; mi < 4; ++mi)
#pragma unroll
    for (int r = 0; r < 4; ++r) {
      const size_t m = (size_t)mt * 128 + wr * 64 + mi * 16 + fq * 4 + r;
#pragma unroll
      for (int ni = 0; ni < 4; ++ni) {
        const int d = nt * 128 + wc * 64 + ni * 16 + fr;
        Pp[m * Dd + d] = acc[mi][ni][r];
      }
    }
}

// ---------------- launch ----------------------------------------------------
extern "C" void kernel_launch(void* const* d_in, const int* in_sizes, int n_in,
                              void* d_out, int out_size, void* d_ws, size_t ws_size,
                              hipStream_t stream) {
  const float* x   = (const float*)d_in[0];
  const float* wts = (const float*)d_in[1];
  const float* w1  = (const float*)d_in[2];
  const float* b1  = (const float*)d_in[3];
  const float* w2  = (const float*)d_in[4];
  const float* b2  = (const float*)d_in[5];
  float* out = (float*)d_out;

  char* ws = (char*)d_ws;
  size_t off = 0;
  bf16* xb  = (bf16*)(ws + off); off += (size_t)Mm * Dd * 2;
  bf16* w1t = (bf16*)(ws + off); off += (size_t)Ee * Hh * Dd * 2;
  bf16* w2t = (bf16*)(ws + off); off += (size_t)Dd * Ee * Hh * 2;

  const size_t gfull = (size_t)Mm * Ee * Hh * 2;  // 134 MB
  const size_t psz   = (size_t)Mm * Dd * 4;       // 16.8 MB

  cvt_x_kernel<<<(Mm * Dd / 4 + 255) / 256, 256, 0, stream>>>(x, xb, Mm * Dd / 4);
  transpose_cvt<<<dim3(Hh / 64, Dd / 64, Ee), 256, 0, stream>>>(
      w1, w1t, Dd, Hh, (size_t)Dd * Hh, (size_t)Hh * Dd, Dd);
  transpose_cvt<<<dim3(Dd / 64, Hh / 64, Ee), 256, 0, stream>>>(
      w2, w2t, Hh, Dd, (size_t)Hh * Dd, (size_t)Hh, Ee * Hh);

  if (ws_size >= off + gfull + 4 * psz) {
    // main path: 256^2 8-phase kernels, split-K S=4
    bf16* G = (bf16*)(ws + off);
    float* P = (float*)(ws + off + gfull);
    ffn_stage1_256<<<dim3(Mm / 256, (Ee * Hh) / 256), 512, 0, stream>>>(
        xb, w1t, b1, wts, G);
    ffn_stage2_256<<<dim3(Mm / 256, Dd / 256, 4), 512, 0, stream>>>(
        G, w2t, P, GKS / 4);
    reduce_bias<<<(Mm * Dd / 4 + 255) / 256, 256, 0, stream>>>(P, wts, b2, out, 4);
  } else if (ws_size >= off + gfull + 2 * psz) {
    // fallback: 128^2 split-K S=2 (R3 proven)
    bf16* G = (bf16*)(ws + off);
    float* P = (float*)(ws + off + gfull);
    ffn_stage1_t<<<dim3(Mm / 128, Hh / 128, Ee), 256, 0, stream>>>(
        xb, w1t, b1, wts, G);
    ffn_stage2_partial<<<dim3(Mm / 128, Dd / 128, 2), 256, 0, stream>>>(
        G, w2t, P, GKS / 2);
    reduce_bias<<<(Mm * Dd / 4 + 255) / 256, 256, 0, stream>>>(P, wts, b2, out, 2);
  }
}